// Round 3
// baseline (913.320 us; speedup 1.0000x reference)
//
#include <hip/hip_runtime.h>
#include <hip/hip_fp16.h>

// MoE gate: logits = x @ W^T (M=32768, N=64, K=4096 fp32), softmax over 64,
// top-8 (vals fp32, idx as float). Split-f16 MFMA GEMM:
//   x = xh + xl, 64*W = wh + wl  (f16 each); logit = (xh*wh + xl*wh + xh*wl)/64
// Near-tie ranks in the top-9 (rel gap < 5e-5) are re-resolved exactly in fp64
// by a tiny second kernel (~0.6% of tokens) -> indices match np exactly.
//
// R3 changes vs R2 (which passed at 795 us):
//  * W pre-split once into d_ws (Whp/Wlp, fragment-blob layout, L2-resident);
//    gate loads B-fragments directly from global -- no W LDS, no W split VALU.
//  * K-loop restructured: double-buffered X LDS, ONE barrier per chunk, and
//    next-chunk global loads issued AFTER the barrier so the compiler's
//    vmcnt(0)-before-s_barrier drain has nothing pending (R2 issued loads
//    before the barrier -> prefetch fully drained each chunk = full HBM
//    latency exposed 64x).
// Verified 16x16x32 layouts: A/B^T lane->[l&15][(l>>4)*8+j]; C/D col=l&15,
// row=(l>>4)*4+reg.

typedef _Float16 half8 __attribute__((ext_vector_type(8)));
typedef float floatx4 __attribute__((ext_vector_type(4)));

constexpr int D = 4096;      // d_hidden
constexpr int NE = 64;       // experts
constexpr int MBLK = 64;     // tokens per block
constexpr int BK = 64;       // k per chunk
constexpr int KCHUNKS = D / BK;

// ws layout (bytes): [0,16) flag counter; [16, 1MB) flagged token ids;
// [1MB, 1.5MB) Whp; [1.5MB, 2MB) Wlp  (each 64*4096 halfs = 512 KB)
constexpr size_t WS_WH_OFF = (size_t)1 << 20;
constexpr size_t WS_WL_OFF = ((size_t)1 << 20) + ((size_t)512 << 10);

__device__ __forceinline__ void split16(const float4& a, const float4& b,
                                        const float4& c, const float4& d, float sc,
                                        half8& h0, half8& h1, half8& l0, half8& l1) {
    float f[16] = {a.x,a.y,a.z,a.w,b.x,b.y,b.z,b.w,c.x,c.y,c.z,c.w,d.x,d.y,d.z,d.w};
#pragma unroll
    for (int i = 0; i < 16; ++i) {
        float v = f[i] * sc;
        _Float16 hi = (_Float16)v;
        _Float16 lo = (_Float16)(v - (float)hi);
        if (i < 8) { h0[i] = hi; l0[i] = lo; }
        else       { h1[i - 8] = hi; l1[i - 8] = lo; }
    }
}

// Pre-split 64*W into f16 hi/lo fragment blobs. Blob layout (halfs):
// off = (((kc*4 + nt)*2 + ks)*64 + lane)*8, lane = (e&15) | ((kk>>3)<<4).
__global__ __launch_bounds__(256) void presplit_w_kernel(
    const float* __restrict__ wg, _Float16* __restrict__ wh, _Float16* __restrict__ wl)
{
    const int gid = (int)blockIdx.x * 256 + (int)threadIdx.x;   // 32768 threads
    const int e = gid >> 9, k8 = gid & 511;
    const float4* src = (const float4*)(wg + (size_t)e * D + k8 * 8);
    float4 a = src[0], b = src[1];
    float f[8] = {a.x,a.y,a.z,a.w,b.x,b.y,b.z,b.w};
    half8 h, l;
#pragma unroll
    for (int i = 0; i < 8; ++i) {
        float v = f[i] * 64.0f;              // scale 64: keeps wl normal-range f16
        _Float16 hi = (_Float16)v;
        h[i] = hi;
        l[i] = (_Float16)(v - (float)hi);
    }
    const int k = k8 * 8, kc = k >> 6, ks = (k >> 5) & 1, kk = k & 31;
    const int lane = (e & 15) | ((kk >> 3) << 4);
    const int nt = e >> 4;
    const size_t off = ((((size_t)kc * 4 + nt) * 2 + ks) * 64 + lane) * 8;
    *(half8*)(wh + off) = h;
    *(half8*)(wl + off) = l;
}

__global__ __launch_bounds__(256, 2) void moe_gate_kernel(
    const float* __restrict__ x,
    const _Float16* __restrict__ whp, const _Float16* __restrict__ wlp,
    float* __restrict__ out_vals, float* __restrict__ out_idx,
    int* __restrict__ flag_ws, int cap)
{
    __shared__ alignas(16) _Float16 Xh[2][MBLK * BK];   // 2 x 8 KB
    __shared__ alignas(16) _Float16 Xl[2][MBLK * BK];   // 2 x 8 KB

    const int tid  = (int)threadIdx.x;
    const int lane = tid & 63;
    const int wv   = tid >> 6;             // wave id == M-tile id
    const int tb   = (int)blockIdx.x * MBLK;

    // X staging: thread = (row, kg): 16 consecutive floats at k = kg*16.
    const int row = tid >> 2, kg = tid & 3;
    const int m = row & 15, mt = row >> 4;
    const float* xp = x + (size_t)(tb + row) * D + kg * 16;
    // frag blob offset (halfs) for this thread's first half8 group:
    const int off0 = ((mt * 2 + (kg >> 1)) * 64 + m + (kg & 1) * 32) * 8;  // +128 for 2nd

    float4 r0, r1, r2, r3;
#define LOADX(kc) do { const float4* p_ = (const float4*)(xp + (size_t)(kc) * BK); \
        r0 = p_[0]; r1 = p_[1]; r2 = p_[2]; r3 = p_[3]; } while (0)
#define STAGEX(nb) do { half8 h0_, h1_, l0_, l1_;                          \
        split16(r0, r1, r2, r3, 1.0f, h0_, h1_, l0_, l1_);                 \
        *(half8*)&Xh[nb][off0]       = h0_; *(half8*)&Xh[nb][off0 + 128] = h1_; \
        *(half8*)&Xl[nb][off0]       = l0_; *(half8*)&Xl[nb][off0 + 128] = l1_; } while (0)

    floatx4 acc[4] = {{0,0,0,0},{0,0,0,0},{0,0,0,0},{0,0,0,0}};

    LOADX(0);
    STAGEX(0);
    __syncthreads();        // nothing vmem-pending here -> barrier drain free
    LOADX(1);               // overlaps chunk 0's MFMA phase

    for (int kc = 0; kc < KCHUNKS; ++kc) {
        const int cur = kc & 1;
#pragma unroll
        for (int ks = 0; ks < 2; ++ks) {
            const half8 ah = *(const half8*)&Xh[cur][((wv * 2 + ks) * 64 + lane) * 8];
            const half8 al = *(const half8*)&Xl[cur][((wv * 2 + ks) * 64 + lane) * 8];
#pragma unroll
            for (int nt = 0; nt < 4; ++nt) {
                const size_t bo = ((((size_t)kc * 4 + nt) * 2 + ks) * 64 + lane) * 8;
                const half8 bh = *(const half8*)(whp + bo);   // L2-resident, coalesced 1KB/wave
                const half8 bl = *(const half8*)(wlp + bo);
                acc[nt] = __builtin_amdgcn_mfma_f32_16x16x32_f16(ah, bh, acc[nt], 0, 0, 0);
                acc[nt] = __builtin_amdgcn_mfma_f32_16x16x32_f16(al, bh, acc[nt], 0, 0, 0);
                acc[nt] = __builtin_amdgcn_mfma_f32_16x16x32_f16(ah, bl, acc[nt], 0, 0, 0);
            }
        }
        if (kc + 1 < KCHUNKS) {
            STAGEX(cur ^ 1);         // split waits on L(kc+1) regs; consumes all vmem
            __syncthreads();         // no pending vmem -> drain free
            if (kc + 2 < KCHUNKS) LOADX(kc + 2);   // issued AFTER barrier
        }
    }
#undef LOADX
#undef STAGEX

    // Epilogue (verified in R2): lane holds experts {nt*16 + (lane&15)} for
    // tokens tb + wv*16 + (lane>>4)*4 + r. Softmax + top-9 via 16-lane
    // xor-shuffles; adjacent near-ties flag the token for fp64 refinement.
    const int g = lane >> 4, c = lane & 15;
    const float inv64 = 0.015625f;           // undo W*64 scale (exact pow2)
#pragma unroll
    for (int r = 0; r < 4; ++r) {
        float s[4];
#pragma unroll
        for (int nt = 0; nt < 4; ++nt) s[nt] = acc[nt][r] * inv64;
        float mx = fmaxf(fmaxf(s[0], s[1]), fmaxf(s[2], s[3]));
#pragma unroll
        for (int off = 1; off < 16; off <<= 1) mx = fmaxf(mx, __shfl_xor(mx, off));
        float p[4]; float t = 0.0f;
#pragma unroll
        for (int nt = 0; nt < 4; ++nt) { p[nt] = expf(s[nt] - mx); t += p[nt]; }
#pragma unroll
        for (int off = 1; off < 16; off <<= 1) t += __shfl_xor(t, off);
        const float inv = 1.0f / t;
#pragma unroll
        for (int nt = 0; nt < 4; ++nt) p[nt] *= inv;

        const int tok = tb + wv * 16 + g * 4 + r;
        float prev = 0.0f;
        bool flagged = false;
#pragma unroll
        for (int i = 0; i < 9; ++i) {
            float bv = p[0]; int bn = 0;
            if (p[1] > bv) { bv = p[1]; bn = 1; }   // strict > : ties -> lower expert
            if (p[2] > bv) { bv = p[2]; bn = 2; }
            if (p[3] > bv) { bv = p[3]; bn = 3; }
            int be = bn * 16 + c;
#pragma unroll
            for (int off = 1; off < 16; off <<= 1) {
                float ov = __shfl_xor(bv, off);
                int   oe = __shfl_xor(be, off);
                if (ov > bv || (ov == bv && oe < be)) { bv = ov; be = oe; }
            }
            if (i > 0 && (prev - bv) < prev * 5e-5f) flagged = true;
            prev = bv;
            if (i < 8 && c == i) {
                out_vals[(size_t)tok * 8 + i] = bv;
                out_idx [(size_t)tok * 8 + i] = (float)be;
            }
            if (c == (be & 15)) p[be >> 4] = -1.0f; // remove winner (scores >= 0)
        }
        if (flagged && c == 0 && cap > 0) {
            int pos = atomicAdd(flag_ws, 1);
            if (pos < cap) flag_ws[4 + pos] = tok;
        }
    }
}

// fp64 exact re-resolution for flagged tokens (near-tied top-9 ranks).
__global__ __launch_bounds__(256) void moe_refine_kernel(
    const float* __restrict__ x, const float* __restrict__ wg,
    float* __restrict__ out_vals, float* __restrict__ out_idx,
    const int* __restrict__ flag_ws, int cap)
{
    const int count = min(flag_ws[0], cap);
    const int* list = flag_ws + 4;
    __shared__ double part[256];
    for (int it = (int)blockIdx.x; it < count; it += (int)gridDim.x) {
        const int tok = list[it];
        const int e = (int)threadIdx.x & 63, ch = (int)threadIdx.x >> 6;
        const float4* xr = (const float4*)(x + (size_t)tok * D + ch * 1024);
        const float4* wr = (const float4*)(wg + (size_t)e * D + ch * 1024);
        double s0 = 0, s1 = 0, s2 = 0, s3 = 0;
#pragma unroll 4
        for (int k = 0; k < 256; ++k) {
            float4 a = xr[k], b = wr[k];
            s0 += (double)a.x * (double)b.x; s1 += (double)a.y * (double)b.y;
            s2 += (double)a.z * (double)b.z; s3 += (double)a.w * (double)b.w;
        }
        part[threadIdx.x] = (s0 + s1) + (s2 + s3);
        __syncthreads();
        if (threadIdx.x < 64) {
            double l = part[e] + part[e + 64] + part[e + 128] + part[e + 192];
            double m = l;
#pragma unroll
            for (int off = 1; off < 64; off <<= 1) m = fmax(m, __shfl_xor(m, off));
            double p = exp(l - m), Z = p;
#pragma unroll
            for (int off = 1; off < 64; off <<= 1) Z += __shfl_xor(Z, off);
            double key = l;
            for (int i = 0; i < 8; ++i) {
                double bk = key; int bi = e; double bp = p;
#pragma unroll
                for (int off = 1; off < 64; off <<= 1) {
                    double ok = __shfl_xor(bk, off);
                    int    oi = __shfl_xor(bi, off);
                    double op = __shfl_xor(bp, off);
                    if (ok > bk || (ok == bk && oi < bi)) { bk = ok; bi = oi; bp = op; }
                }
                if (e == i) {
                    out_vals[(size_t)tok * 8 + i] = (float)(bp / Z);
                    out_idx [(size_t)tok * 8 + i] = (float)bi;
                }
                if (e == bi) key = -1.0e300;
            }
        }
        __syncthreads();
    }
}

extern "C" void kernel_launch(void* const* d_in, const int* in_sizes, int n_in,
                              void* d_out, int out_size, void* d_ws, size_t ws_size,
                              hipStream_t stream) {
    const float* x  = (const float*)d_in[0];
    const float* wg = (const float*)d_in[1];
    const int n_tokens = in_sizes[0] / D;           // 32768
    float* out_vals = (float*)d_out;
    float* out_idx  = out_vals + (size_t)n_tokens * 8;
    _Float16* wh = (_Float16*)((char*)d_ws + WS_WH_OFF);
    _Float16* wl = (_Float16*)((char*)d_ws + WS_WL_OFF);
    int cap = n_tokens;
    if ((size_t)(16 + cap * 4) > WS_WH_OFF) cap = (int)((WS_WH_OFF - 16) / 4);

    hipMemsetAsync(d_ws, 0, 16, stream);            // zero flag counter
    hipLaunchKernelGGL(presplit_w_kernel, dim3(NE * (D / 8) / 256), dim3(256), 0, stream,
                       wg, wh, wl);
    hipLaunchKernelGGL(moe_gate_kernel, dim3(n_tokens / MBLK), dim3(256), 0, stream,
                       x, wh, wl, out_vals, out_idx, (int*)d_ws, cap);
    hipLaunchKernelGGL(moe_refine_kernel, dim3(256), dim3(256), 0, stream,
                       x, wg, out_vals, out_idx, (const int*)d_ws, cap);
}